// Round 2
// baseline (329.262 us; speedup 1.0000x reference)
//
#include <hip/hip_runtime.h>

typedef __attribute__((ext_vector_type(8))) __bf16 bf16x8;
typedef __attribute__((ext_vector_type(4))) float floatx4;

static __device__ __forceinline__ floatx4 mfma16(bf16x8 a, bf16x8 b, floatx4 c) {
  return __builtin_amdgcn_mfma_f32_16x16x32_bf16(a, b, c, 0, 0, 0);
}

static __device__ __forceinline__ unsigned short f2b_bits(float f) {
  __bf16 h = (__bf16)f;
  return __builtin_bit_cast(unsigned short, h);
}

// async global -> LDS, 16B per lane. LDS dest is wave-uniform base + lane*16.
static __device__ __forceinline__ void stage16(const void* g, void* l) {
  __builtin_amdgcn_global_load_lds(
      (__attribute__((address_space(1))) void*)(unsigned long long)g,
      (__attribute__((address_space(3))) void*)(unsigned int)(unsigned long long)l,
      16, 0, 0);
}

// ---------------------------------------------------------------- cast + zero lsum
__global__ void cast_kernel(const float4* __restrict__ x, const float4* __restrict__ w,
                            ushort4* __restrict__ xb, ushort4* __restrict__ wb,
                            float* __restrict__ lsum) {
  int i = blockIdx.x * 256 + threadIdx.x;
  if (i < 4194304) {
    float4 v = x[i];
    ushort4 o;
    o.x = f2b_bits(v.x); o.y = f2b_bits(v.y); o.z = f2b_bits(v.z); o.w = f2b_bits(v.w);
    xb[i] = o;
  } else if (i < 4456448) {
    int j = i - 4194304;
    float4 v = w[j];
    ushort4 o;
    o.x = f2b_bits(v.x); o.y = f2b_bits(v.y); o.z = f2b_bits(v.z); o.w = f2b_bits(v.w);
    wb[j] = o;
  } else {
    int j = i - 4456448;
    if (j < 16384) lsum[j] = 0.0f;
  }
}

// ================================================================ 128x256 engine, BK=32
// 512 threads = 8 waves: wr = wid>>2 (2 row-halves of 64), wc = wid&3 (4 col-quarters of 64).
// Per-wave C = 64x64 -> acc[4][4] = 64 VGPR. LDS 48 KiB = A[2][8][64] + B[2][16][64] bf16x8
// chunks in MFMA fragment order (row = rg*16 + lr, k = lq*8..+7) -> conflict-free b128.
// One __syncthreads per K-tile (compiler adds vmcnt0/lgkm0); latency hidden by 2 blocks/CU.
// Stage work per K-tile: A 8 KiB (1 gload_lds/thread) + B 16 KiB (2/thread).

// ---------------------------------------------------------------- z^T = (x @ W^T)^T
__global__ __launch_bounds__(512, 4) void gemm_zT(const unsigned short* __restrict__ xb,
                                                  const unsigned short* __restrict__ wb,
                                                  unsigned short* __restrict__ zT) {
  extern __shared__ bf16x8 lds[];
  bf16x8* ldsA = lds;          // [2][8][64]
  bf16x8* ldsB = lds + 1024;   // [2][16][64]
  const int tid = threadIdx.x, wid = tid >> 6, lane = tid & 63;
  const int wr = wid >> 2, wc = wid & 3, lr = lane & 15, lq = lane >> 4;
  const int g = blockIdx.x, b = g & 7, gg = g >> 3;
  const int mt = gg >> 2, ntl = gg & 3;  // 16 M-tiles(128) x 4 N-tiles(256) x 8 b = 512

  const unsigned short* gA = xb + (size_t)b * 2097152 + (size_t)(mt * 128 + lr) * 1024 + lq * 8;
  const unsigned short* gB = wb + (size_t)(ntl * 256 + lr) * 1024 + lq * 8;
  floatx4 acc[4][4] = {};

  stage16(gA + wid * 16384, &ldsA[wid * 64]);
  stage16(gB + wid * 16384, &ldsB[wid * 64]);
  stage16(gB + (wid + 8) * 16384, &ldsB[(wid + 8) * 64]);
  __syncthreads();

#pragma unroll
  for (int kt = 0; kt < 32; ++kt) {
    const int c = kt & 1;
    if (kt + 1 < 32) {
      const int k1 = (kt + 1) * 32;
      stage16(gA + wid * 16384 + k1, &ldsA[(c ^ 1) * 512 + wid * 64]);
      stage16(gB + wid * 16384 + k1, &ldsB[(c ^ 1) * 1024 + wid * 64]);
      stage16(gB + (wid + 8) * 16384 + k1, &ldsB[(c ^ 1) * 1024 + (wid + 8) * 64]);
    }
    bf16x8 a_[4], b_[4];
#pragma unroll
    for (int i = 0; i < 4; ++i) a_[i] = ldsA[c * 512 + (wr * 4 + i) * 64 + lane];
#pragma unroll
    for (int j = 0; j < 4; ++j) b_[j] = ldsB[c * 1024 + (wc * 4 + j) * 64 + lane];
#pragma unroll
    for (int i = 0; i < 4; ++i)
#pragma unroll
      for (int j = 0; j < 4; ++j) acc[i][j] = mfma16(a_[i], b_[j], acc[i][j]);
    __syncthreads();
  }

#pragma unroll
  for (int i = 0; i < 4; ++i) {
    const int m = mt * 128 + wr * 64 + i * 16 + lq * 4;
#pragma unroll
    for (int j = 0; j < 4; ++j) {
      const int e = ntl * 256 + wc * 64 + j * 16 + lr;
      ushort4 o;
      o.x = f2b_bits(acc[i][j][0]); o.y = f2b_bits(acc[i][j][1]);
      o.z = f2b_bits(acc[i][j][2]); o.w = f2b_bits(acc[i][j][3]);
      *(ushort4*)(zT + ((size_t)(b * 1024 + e)) * 2048 + m) = o;
    }
  }
}

// ---------------------------------------------------------------- QK^T + exp epilogue
// Blocks: 8 b x 72 tiles (row128 rt x col256 ct, ct <= rt>>1) = 576.
__global__ __launch_bounds__(512, 4) void qk_exp(const unsigned short* __restrict__ xb,
                                                 unsigned short* __restrict__ P,
                                                 float* __restrict__ lsum) {
  extern __shared__ bf16x8 lds[];
  bf16x8* ldsA = lds;
  bf16x8* ldsB = lds + 1024;
  const int tid = threadIdx.x, wid = tid >> 6, lane = tid & 63;
  const int wr = wid >> 2, wc = wid & 3, lr = lane & 15, lq = lane >> 4;
  const int g = blockIdx.x, b = g & 7, idx = g >> 3;  // idx in 0..71
  int m = (int)((sqrtf(4.0f * idx + 1.0f) - 1.0f) * 0.5f);
  while ((m + 1) * (m + 2) <= idx) ++m;
  while (m * (m + 1) > idx) --m;
  const int rem = idx - m * (m + 1);
  const int rt = 2 * m + (rem > m);
  const int ct = rem - (rem > m ? (m + 1) : 0);

  const unsigned short* xbb = xb + (size_t)b * 2097152;
  const unsigned short* gA = xbb + (size_t)(rt * 128 + lr) * 1024 + lq * 8;
  const unsigned short* gB = xbb + (size_t)(ct * 256 + lr) * 1024 + lq * 8;
  floatx4 acc[4][4] = {};

  stage16(gA + wid * 16384, &ldsA[wid * 64]);
  stage16(gB + wid * 16384, &ldsB[wid * 64]);
  stage16(gB + (wid + 8) * 16384, &ldsB[(wid + 8) * 64]);
  __syncthreads();

#pragma unroll
  for (int kt = 0; kt < 32; ++kt) {
    const int c = kt & 1;
    if (kt + 1 < 32) {
      const int k1 = (kt + 1) * 32;
      stage16(gA + wid * 16384 + k1, &ldsA[(c ^ 1) * 512 + wid * 64]);
      stage16(gB + wid * 16384 + k1, &ldsB[(c ^ 1) * 1024 + wid * 64]);
      stage16(gB + (wid + 8) * 16384 + k1, &ldsB[(c ^ 1) * 1024 + (wid + 8) * 64]);
    }
    bf16x8 a_[4], b_[4];
#pragma unroll
    for (int i = 0; i < 4; ++i) a_[i] = ldsA[c * 512 + (wr * 4 + i) * 64 + lane];
#pragma unroll
    for (int j = 0; j < 4; ++j) b_[j] = ldsB[c * 1024 + (wc * 4 + j) * 64 + lane];
#pragma unroll
    for (int i = 0; i < 4; ++i)
#pragma unroll
      for (int j = 0; j < 4; ++j) acc[i][j] = mfma16(a_[i], b_[j], acc[i][j]);
    __syncthreads();
  }

  const int col128 = 2 * ct + (wc >> 1);
  if (col128 <= rt) {  // strictly-upper 128-tiles have no slot in the tri packing
    const bool diag = (col128 == rt);
    unsigned short* Pt =
        P + ((size_t)b * 136 + (size_t)(rt * (rt + 1) / 2 + col128)) * 16384;
    float* lsb = lsum + b * 2048 + rt * 128;
#pragma unroll
    for (int i = 0; i < 4; ++i) {
      const int row_l = wr * 64 + i * 16 + lq * 4;
      floatx4 rs = {0.0f, 0.0f, 0.0f, 0.0f};
#pragma unroll
      for (int j = 0; j < 4; ++j) {
        const int incol = (wc & 1) * 64 + j * 16 + lr;
#pragma unroll
        for (int v = 0; v < 4; ++v) {
          float p = __expf(acc[i][j][v] * 0.03125f - 44.0f);
          if (diag && incol > row_l + v) p = 0.0f;
          Pt[(row_l + v) * 128 + incol] = f2b_bits(p);
          rs[v] += p;
        }
      }
#pragma unroll
      for (int v = 0; v < 4; ++v) {
        float s = rs[v];
        s += __shfl_xor(s, 1);
        s += __shfl_xor(s, 2);
        s += __shfl_xor(s, 4);
        s += __shfl_xor(s, 8);
        if (lr == 0) atomicAdd(&lsb[row_l + v], s);
      }
    }
  }
}

// ---------------------------------------------------------------- O = P @ z, divide by lsum
// Blocks: 8 b x 16 rt x 4 ntl = 512; K = (rt+1)*128 exact (tri-packed P, no zero-fill).
__global__ __launch_bounds__(512, 4) void pv_out(const unsigned short* __restrict__ P,
                                                 const unsigned short* __restrict__ zT,
                                                 const float* __restrict__ lsum,
                                                 float* __restrict__ out) {
  extern __shared__ bf16x8 lds[];
  bf16x8* ldsA = lds;
  bf16x8* ldsB = lds + 1024;
  const int tid = threadIdx.x, wid = tid >> 6, lane = tid & 63;
  const int wr = wid >> 2, wc = wid & 3, lr = lane & 15, lq = lane >> 4;
  const int g = blockIdx.x, b = g & 7, gg = g >> 3;
  const int rt = 15 - (gg >> 2), ntl = gg & 3;  // long K first
  const int NKT = (rt + 1) * 4;                 // BK=32 tiles: 4..64

  const unsigned short* pA = P + (size_t)b * 136 * 16384 +
                             (size_t)(rt * (rt + 1) / 2) * 16384 + lr * 128 + lq * 8;
  const unsigned short* gB =
      zT + (size_t)b * 2097152 + ((size_t)(ntl * 256) + lr) * 2048 + lq * 8;
  floatx4 acc[4][4] = {};

  stage16(pA + wid * 2048, &ldsA[wid * 64]);
  stage16(gB + wid * 32768, &ldsB[wid * 64]);
  stage16(gB + (wid + 8) * 32768, &ldsB[(wid + 8) * 64]);
  __syncthreads();

  for (int kt = 0; kt < NKT; ++kt) {
    const int c = kt & 1;
    if (kt + 1 < NKT) {
      const int k1 = kt + 1;
      stage16(pA + wid * 2048 + (k1 >> 2) * 16384 + (k1 & 3) * 32,
              &ldsA[(c ^ 1) * 512 + wid * 64]);
      stage16(gB + wid * 32768 + k1 * 32, &ldsB[(c ^ 1) * 1024 + wid * 64]);
      stage16(gB + (wid + 8) * 32768 + k1 * 32, &ldsB[(c ^ 1) * 1024 + (wid + 8) * 64]);
    }
    bf16x8 a_[4], b_[4];
#pragma unroll
    for (int i = 0; i < 4; ++i) a_[i] = ldsA[c * 512 + (wr * 4 + i) * 64 + lane];
#pragma unroll
    for (int j = 0; j < 4; ++j) b_[j] = ldsB[c * 1024 + (wc * 4 + j) * 64 + lane];
#pragma unroll
    for (int i = 0; i < 4; ++i)
#pragma unroll
      for (int j = 0; j < 4; ++j) acc[i][j] = mfma16(a_[i], b_[j], acc[i][j]);
    __syncthreads();
  }

  const float* lsb = lsum + b * 2048 + rt * 128;
  float* outb = out + (size_t)b * 2097152;
#pragma unroll
  for (int i = 0; i < 4; ++i) {
    const int row_l = wr * 64 + i * 16 + lq * 4;
    floatx4 linv;
#pragma unroll
    for (int v = 0; v < 4; ++v) linv[v] = 1.0f / lsb[row_l + v];
#pragma unroll
    for (int j = 0; j < 4; ++j) {
      const int col = ntl * 256 + wc * 64 + j * 16 + lr;
#pragma unroll
      for (int v = 0; v < 4; ++v)
        outb[(size_t)(rt * 128 + row_l + v) * 1024 + col] = acc[i][j][v] * linv[v];
    }
  }
}

// ---------------------------------------------------------------- launcher
extern "C" void kernel_launch(void* const* d_in, const int* in_sizes, int n_in,
                              void* d_out, int out_size, void* d_ws, size_t ws_size,
                              hipStream_t stream) {
  const float* x = (const float*)d_in[0];  // [8][2048][1024]
  const float* W = (const float*)d_in[1];  // [1024][1024]
  float* out = (float*)d_out;              // [8][2048][1024]
  char* ws = (char*)d_ws;
  unsigned short* xb = (unsigned short*)ws;                          // 32 MiB bf16 x
  unsigned short* zT = (unsigned short*)(ws + 33554432ull);          // 32 MiB bf16 z^T
  unsigned short* P  = (unsigned short*)(ws + 67108864ull);          // 34 MiB packed tri P
  unsigned short* wb = P;  // alias: wb consumed by gemm_zT before P is written
  float* lsum = (float*)(ws + 67108864ull + 35651584ull);            // 64 KiB row sums

  static bool attr_done = false;
  if (!attr_done) {
    (void)hipFuncSetAttribute(reinterpret_cast<const void*>(gemm_zT),
                              hipFuncAttributeMaxDynamicSharedMemorySize, 49152);
    (void)hipFuncSetAttribute(reinterpret_cast<const void*>(qk_exp),
                              hipFuncAttributeMaxDynamicSharedMemorySize, 49152);
    (void)hipFuncSetAttribute(reinterpret_cast<const void*>(pv_out),
                              hipFuncAttributeMaxDynamicSharedMemorySize, 49152);
    attr_done = true;
  }

  cast_kernel<<<17472, 256, 0, stream>>>((const float4*)x, (const float4*)W,
                                         (ushort4*)xb, (ushort4*)wb, lsum);
  gemm_zT<<<512, 512, 49152, stream>>>(xb, wb, zT);
  qk_exp<<<576, 512, 49152, stream>>>(xb, P, lsum);
  pv_out<<<512, 512, 49152, stream>>>(P, zT, lsum, out);
}